// Round 5
// baseline (204.788 us; speedup 1.0000x reference)
//
#include <hip/hip_runtime.h>

#define IN_FEAT 4096
#define OUT_FEAT 4096
#define RANK 1024
#define TOK 8192   // B*S = 4*2048

typedef _Float16 f16x8 __attribute__((ext_vector_type(8)));
typedef _Float16 f16x4 __attribute__((ext_vector_type(4)));
typedef float f32x4 __attribute__((ext_vector_type(4)));

#define GLD_LDS16(g, l)                                                         \
  __builtin_amdgcn_global_load_lds(                                             \
      (__attribute__((address_space(1))) const void*)(g),                       \
      (__attribute__((address_space(3))) void*)(l), 16, 0, 0)

#define MIDBAR()                                        \
  __builtin_amdgcn_s_barrier();                         \
  asm volatile("s_waitcnt lgkmcnt(0)" ::: "memory")
#define ENDBAR() __builtin_amdgcn_s_barrier()

// ---------------------------------------------------------------------------
// 2:4 soft-threshold sparsify, scale, cast to fp16.
// ---------------------------------------------------------------------------

__device__ __forceinline__ void soft24(const float4 g, float s,
                                       float& r0, float& r1, float& r2, float& r3) {
  const float m0 = fabsf(g.x), m1 = fabsf(g.y), m2 = fabsf(g.z), m3 = fabsf(g.w);
  const float lo1 = fminf(m0, m1), hi1 = fmaxf(m0, m1);
  const float lo2 = fminf(m2, m3), hi2 = fmaxf(m2, m3);
  const float t = fminf(fmaxf(lo1, lo2), fminf(hi1, hi2));  // 2nd smallest
  r0 = copysignf(fmaxf(m0 - t, 0.0f), g.x) * s;
  r1 = copysignf(fmaxf(m1 - t, 0.0f), g.y) * s;
  r2 = copysignf(fmaxf(m2 - t, 0.0f), g.z) * s;
  r3 = copysignf(fmaxf(m3 - t, 0.0f), g.w) * s;
}

__global__ __launch_bounds__(256) void sparsify_A_kernel(
    const float* __restrict__ wA, const float* __restrict__ scaleA,
    _Float16* __restrict__ waT) {
  const int idx = blockIdx.x * 256 + threadIdx.x;
  const int i = idx & (IN_FEAT - 1);
  const int jg = idx >> 12;
  const float4 g = *reinterpret_cast<const float4*>(wA + (size_t)i * RANK + jg * 4);
  const float s = scaleA[0];
  float r0, r1, r2, r3;
  soft24(g, s, r0, r1, r2, r3);
  const size_t base = (size_t)(jg * 4) * IN_FEAT + i;
  waT[base] = (_Float16)r0;
  waT[base + IN_FEAT] = (_Float16)r1;
  waT[base + 2 * IN_FEAT] = (_Float16)r2;
  waT[base + 3 * IN_FEAT] = (_Float16)r3;
}

__global__ __launch_bounds__(256) void sparsify_B_kernel(
    const float* __restrict__ wB, const float* __restrict__ scaleB,
    _Float16* __restrict__ wbs) {
  const int idx = blockIdx.x * 256 + threadIdx.x;
  const float4 g = *reinterpret_cast<const float4*>(wB + (size_t)idx * 4);
  const float s = scaleB[0];
  float r0, r1, r2, r3;
  soft24(g, s, r0, r1, r2, r3);
  f16x4 h;
  h[0] = (_Float16)r0; h[1] = (_Float16)r1; h[2] = (_Float16)r2; h[3] = (_Float16)r3;
  *reinterpret_cast<f16x4*>(wbs + (size_t)idx * 4) = h;
}

__global__ __launch_bounds__(256) void cast_x_kernel(
    const float* __restrict__ x, _Float16* __restrict__ x16) {
  const size_t i = ((size_t)blockIdx.x * 256 + threadIdx.x) * 8;
  const float4 f0 = *reinterpret_cast<const float4*>(x + i);
  const float4 f1 = *reinterpret_cast<const float4*>(x + i + 4);
  f16x8 h;
  h[0] = (_Float16)f0.x; h[1] = (_Float16)f0.y;
  h[2] = (_Float16)f0.z; h[3] = (_Float16)f0.w;
  h[4] = (_Float16)f1.x; h[5] = (_Float16)f1.y;
  h[6] = (_Float16)f1.z; h[7] = (_Float16)f1.w;
  *reinterpret_cast<f16x8*>(x16 + i) = h;
}

// ---------------------------------------------------------------------------
// 128x128-tile GEMM (verified R1/R2) — fallback path only.
// ---------------------------------------------------------------------------
template <int N, int K, bool A_F32, bool OUT_F16>
__global__ __launch_bounds__(256, 4) void gemm128(
    const void* __restrict__ Av, const _Float16* __restrict__ Bh,
    void* __restrict__ Cv, const float* __restrict__ bias) {
  __shared__ __attribute__((aligned(128))) char lds[32768];
  char* ldsA = lds;
  char* ldsB = lds + 16384;

  const int tid = threadIdx.x;
  const int lane = tid & 63;
  const int w = tid >> 6;
  const int wrow = (w >> 1) * 64;
  const int wcol = (w & 1) * 64;

  constexpr int GX = N / 128;
  const int nwg = GX * (TOK / 128);
  const int l = blockIdx.y * GX + blockIdx.x;
  const int wg = (l & 7) * (nwg >> 3) + (l >> 3);
  const int brow = (wg / GX) * 128;
  const int bcol = (wg % GX) * 128;

  f32x4 acc[4][4] = {};

  for (int k0 = 0; k0 < K; k0 += 64) {
    __syncthreads();
#pragma unroll
    for (int it = 0; it < 4; ++it) {
      const int c = it * 256 + tid;
      const int row = c >> 3;
      const int u = c & 7;
      const _Float16* gsrc =
          Bh + (size_t)(bcol + row) * K + k0 + ((u ^ (row & 7)) << 3);
      GLD_LDS16(gsrc, ldsB + c * 16);
    }
    if constexpr (A_F32) {
      const float* Af = (const float*)Av;
#pragma unroll
      for (int it = 0; it < 4; ++it) {
        const int c = it * 256 + tid;
        const int row = c >> 3;
        const int u = c & 7;
        const float* gsrc = Af + (size_t)(brow + row) * K + k0 + (u << 3);
        const float4 f0 = *reinterpret_cast<const float4*>(gsrc);
        const float4 f1 = *reinterpret_cast<const float4*>(gsrc + 4);
        f16x8 h;
        h[0] = (_Float16)f0.x; h[1] = (_Float16)f0.y;
        h[2] = (_Float16)f0.z; h[3] = (_Float16)f0.w;
        h[4] = (_Float16)f1.x; h[5] = (_Float16)f1.y;
        h[6] = (_Float16)f1.z; h[7] = (_Float16)f1.w;
        *reinterpret_cast<f16x8*>(ldsA + row * 128 + ((u ^ (row & 7)) << 4)) = h;
      }
    } else {
      const _Float16* Ah = (const _Float16*)Av;
#pragma unroll
      for (int it = 0; it < 4; ++it) {
        const int c = it * 256 + tid;
        const int row = c >> 3;
        const int u = c & 7;
        const _Float16* gsrc =
            Ah + (size_t)(brow + row) * K + k0 + ((u ^ (row & 7)) << 3);
        GLD_LDS16(gsrc, ldsA + c * 16);
      }
    }
    __syncthreads();
#pragma unroll
    for (int kk = 0; kk < 2; ++kk) {
      f16x8 af[4], bf[4];
#pragma unroll
      for (int m = 0; m < 4; ++m) {
        const int row = wrow + m * 16 + (lane & 15);
        const int u = (kk * 4 + (lane >> 4)) ^ (row & 7);
        af[m] = *reinterpret_cast<const f16x8*>(ldsA + row * 128 + u * 16);
      }
#pragma unroll
      for (int n = 0; n < 4; ++n) {
        const int row = wcol + n * 16 + (lane & 15);
        const int u = (kk * 4 + (lane >> 4)) ^ (row & 7);
        bf[n] = *reinterpret_cast<const f16x8*>(ldsB + row * 128 + u * 16);
      }
#pragma unroll
      for (int m = 0; m < 4; ++m)
#pragma unroll
        for (int n = 0; n < 4; ++n)
          acc[m][n] =
              __builtin_amdgcn_mfma_f32_16x16x32_f16(af[m], bf[n], acc[m][n], 0, 0, 0);
    }
  }

  const int r4 = (lane >> 4) * 4;
  const int cl = lane & 15;
  if constexpr (OUT_F16) {
    _Float16* C = (_Float16*)Cv;
#pragma unroll
    for (int m = 0; m < 4; ++m)
#pragma unroll
      for (int n = 0; n < 4; ++n)
#pragma unroll
        for (int j = 0; j < 4; ++j) {
          const int rr = brow + wrow + m * 16 + r4 + j;
          const int cc = bcol + wcol + n * 16 + cl;
          C[(size_t)rr * N + cc] = (_Float16)acc[m][n][j];
        }
  } else {
    float* C = (float*)Cv;
#pragma unroll
    for (int n = 0; n < 4; ++n) {
      const int cc = bcol + wcol + n * 16 + cl;
      const float bv = bias[cc];
#pragma unroll
      for (int m = 0; m < 4; ++m)
#pragma unroll
        for (int j = 0; j < 4; ++j) {
          const int rr = brow + wrow + m * 16 + r4 + j;
          C[(size_t)rr * N + cc] = acc[m][n][j] + bv;
        }
    }
  }
}

// ---------------------------------------------------------------------------
// GEMM1: 128(M)x256(N)-tile, ONE phase per K-tile (32 MFMA / barrier pair),
// triple-buffered LDS (A 3x16KB @0, B 3x32KB @49152 = 144 KB).
// Stage tile t+2 during tile t; vmcnt(6) leaves t+2's 6 loads in flight and
// guarantees t+1's have landed. Swapped-operand MFMA -> f16x4 epilogue.
// ---------------------------------------------------------------------------
template <int M, int N, int K>
__global__ __launch_bounds__(512, 2) void gemm1_m(
    const _Float16* __restrict__ A, const _Float16* __restrict__ B,
    _Float16* __restrict__ C) {
  extern __shared__ char lds[];

  const int tid = threadIdx.x;
  const int lane = tid & 63;
  const int w = tid >> 6;
  const int wr = w >> 2;   // 0..1 (M)
  const int wc = w & 3;    // 0..3 (N)
  const int l15 = lane & 15;
  const int ubase = lane >> 4;

  constexpr int GX = N / 256;           // 4
  constexpr int NWG = GX * (M / 128);   // 256
  const int l = blockIdx.y * GX + blockIdx.x;
  const int wg = (l & 7) * (NWG >> 3) + (l >> 3);
  const int brow = (wg / GX) * 128;
  const int bcol = (wg % GX) * 256;

  f32x4 acc[4][4] = {};
  f16x8 af[4][2], bf[4][2];

  auto stageA = [&](int kof, int slot) {
#pragma unroll
    for (int r = 0; r < 2; ++r) {
      const int c = r * 512 + tid;
      const int row = c >> 3;
      const int u = c & 7;
      GLD_LDS16(A + (size_t)(brow + row) * K + kof + ((u ^ (row & 7)) << 3),
                lds + slot * 16384 + c * 16);
    }
  };
  auto stageB = [&](int kof, int slot) {
#pragma unroll
    for (int r = 0; r < 4; ++r) {
      const int c = r * 512 + tid;
      const int row = c >> 3;
      const int u = c & 7;
      GLD_LDS16(B + (size_t)(bcol + row) * K + kof + ((u ^ (row & 7)) << 3),
                lds + 49152 + slot * 32768 + c * 16);
    }
  };

  constexpr int NT = K / 64;  // 64 K-tiles

  // prologue: stage tiles 0 and 1; wait tile 0 (6 loads still in flight)
  stageA(0, 0);
  stageB(0, 0);
  stageA(64, 1);
  stageB(64, 1);
  asm volatile("s_waitcnt vmcnt(6)" ::: "memory");
  __builtin_amdgcn_s_barrier();

  int slot = 0;
  for (int t = 0; t < NT; ++t) {
    // ds-reads for tile t (16 x ds_read_b128)
#pragma unroll
    for (int i = 0; i < 4; ++i)
#pragma unroll
      for (int ks = 0; ks < 2; ++ks) {
        const int row = wr * 64 + i * 16 + l15;
        const int u = (ks * 4 + ubase) ^ (row & 7);
        af[i][ks] =
            *reinterpret_cast<const f16x8*>(lds + slot * 16384 + row * 128 + u * 16);
      }
#pragma unroll
    for (int j = 0; j < 4; ++j)
#pragma unroll
      for (int ks = 0; ks < 2; ++ks) {
        const int row = wc * 64 + j * 16 + l15;
        const int u = (ks * 4 + ubase) ^ (row & 7);
        bf[j][ks] = *reinterpret_cast<const f16x8*>(lds + 49152 + slot * 32768 +
                                                    row * 128 + u * 16);
      }
    // stage tile t+2 into slot (t+2)%3 (last read ended >=1 ENDBAR ago)
    if (t + 2 < NT) {
      int s2 = slot + 2;
      if (s2 >= 3) s2 -= 3;
      stageA((t + 2) * 64, s2);
      stageB((t + 2) * 64, s2);
      asm volatile("s_waitcnt vmcnt(6)" ::: "memory");  // t+1 landed
    } else if (t + 2 == NT) {
      asm volatile("s_waitcnt vmcnt(0)" ::: "memory");  // drain last buffer
    }
    MIDBAR();
    __builtin_amdgcn_s_setprio(1);
#pragma unroll
    for (int ks = 0; ks < 2; ++ks)
#pragma unroll
      for (int i = 0; i < 4; ++i)
#pragma unroll
        for (int j = 0; j < 4; ++j)
          acc[i][j] = __builtin_amdgcn_mfma_f32_16x16x32_f16(
              bf[j][ks], af[i][ks], acc[i][j], 0, 0, 0);  // swapped operands
    __builtin_amdgcn_s_setprio(0);
    ENDBAR();
    ++slot;
    if (slot == 3) slot = 0;
  }

  // epilogue (swapped layout): M = lane&15, N = (lane>>4)*4 + j
  const int r4 = (lane >> 4) * 4;
#pragma unroll
  for (int m = 0; m < 4; ++m)
#pragma unroll
    for (int n = 0; n < 4; ++n) {
      const int rr = brow + wr * 64 + m * 16 + l15;
      const int cc = bcol + wc * 64 + n * 16 + r4;
      f16x4 h;
#pragma unroll
      for (int j = 0; j < 4; ++j) h[j] = (_Float16)acc[m][n][j];
      *reinterpret_cast<f16x4*>(C + (size_t)rr * N + cc) = h;
    }
}

// ---------------------------------------------------------------------------
// GEMM2: 256x256-tile, merged 4 phases per 2 K-tiles (32 MFMA / barrier pair),
// same R3 double-buffer slot schedule + counted vmcnt(4).
// Swapped-operand MFMA -> float4 epilogue with float4 bias.
// LDS 128 KiB: AOFF/BOFF as before.
// ---------------------------------------------------------------------------
#define AOFF(s, h) (((s) * 2 + (h)) * 16384)
#define BOFF(s, h) (65536 + ((s) * 2 + (h)) * 16384)

template <int M, int N, int K>
__global__ __launch_bounds__(512, 2) void gemm2_m(
    const _Float16* __restrict__ A, const _Float16* __restrict__ B,
    float* __restrict__ C, const float* __restrict__ bias) {
  extern __shared__ char lds[];

  const int tid = threadIdx.x;
  const int lane = tid & 63;
  const int w = tid >> 6;
  const int wr = w >> 2;
  const int wc = w & 3;
  const int l15 = lane & 15;
  const int ubase = lane >> 4;

  constexpr int GX = N / 256;
  constexpr int NWG = GX * (M / 256);
  const int l = blockIdx.y * GX + blockIdx.x;
  const int wg = (l & 7) * (NWG >> 3) + (l >> 3);
  const int brow = (wg / GX) * 256;
  const int bcol = (wg % GX) * 256;

  const _Float16* Abase = A + (size_t)brow * K;
  const _Float16* Bbase = B + (size_t)bcol * K;

  auto stage = [&](const _Float16* srcBase, int rowOff, int kof, int ldsOff) {
#pragma unroll
    for (int r = 0; r < 2; ++r) {
      const int c = r * 512 + tid;
      const int row = c >> 3;
      const int u = c & 7;
      const _Float16* g =
          srcBase + (size_t)(rowOff + row) * K + kof + ((u ^ (row & 7)) << 3);
      GLD_LDS16(g, lds + ldsOff + c * 16);
    }
  };

  f32x4 acc[8][4] = {};
  f16x8 af[4][2], bf01[2][2], bf23[2][2];

#define LDA_GRP(SLOT, MBASE)                                                   \
  _Pragma("unroll") for (int i = 0; i < 4; ++i)                                \
  _Pragma("unroll") for (int ks = 0; ks < 2; ++ks) {                           \
    const int row = ((MBASE) + i) * 16 + l15;                                  \
    const int u = (ks * 4 + ubase) ^ (row & 7);                                \
    af[i][ks] = *reinterpret_cast<const f16x8*>(                               \
        lds + AOFF(SLOT, wr) + row * 128 + u * 16);                            \
  }
#define LDB_GRP(SLOT, NBASE, DST)                                              \
  _Pragma("unroll") for (int j = 0; j < 2; ++j)                                \
  _Pragma("unroll") for (int ks = 0; ks < 2; ++ks) {                           \
    const int row = (wc & 1) * 64 + ((NBASE) + j) * 16 + l15;                  \
    const int u = (ks * 4 + ubase) ^ (row & 7);                                \
    DST[j][ks] = *reinterpret_cast<const f16x8*>(                              \
        lds + BOFF(SLOT, wc >> 1) + row * 128 + u * 16);                       \
  }

  // 32 MFMA: quadrants (MO,0..3), swapped operands
#define MFMA32(MO)                                                             \
  __builtin_amdgcn_s_setprio(1);                                               \
  _Pragma("unroll") for (int ks = 0; ks < 2; ++ks)                             \
  _Pragma("unroll") for (int i = 0; i < 4; ++i)                                \
  _Pragma("unroll") for (int j = 0; j < 2; ++j) {                              \
    acc[(MO) + i][j] = __builtin_amdgcn_mfma_f32_16x16x32_f16(                 \
        bf01[j][ks], af[i][ks], acc[(MO) + i][j], 0, 0, 0);                    \
    acc[(MO) + i][2 + j] = __builtin_amdgcn_mfma_f32_16x16x32_f16(             \
        bf23[j][ks], af[i][ks], acc[(MO) + i][2 + j], 0, 0, 0);                \
  }                                                                            \
  __builtin_amdgcn_s_setprio(0);

  constexpr int NT = K / 64;

  // prologue: A(0), B(0), B(1); vmcnt(4) -> A0,B0 landed, B1 in flight
  stage(Abase, 0, 0, AOFF(0, 0));
  stage(Abase, 128, 0, AOFF(0, 1));
  stage(Bbase, 0, 0, BOFF(0, 0));
  stage(Bbase, 128, 0, BOFF(0, 1));
  stage(Bbase, 0, 64, BOFF(1, 0));
  stage(Bbase, 128, 64, BOFF(1, 1));
  asm volatile("s_waitcnt vmcnt(4)" ::: "memory");
  __builtin_amdgcn_s_barrier();

  for (int tt = 0; tt < NT; tt += 2) {
    const bool last = (tt + 2 >= NT);
    const int kof1 = tt * 64 + 64;
    const int kof2 = tt * 64 + 128;
    const int kof3 = tt * 64 + 192;

    // MPH1: tile t, rows 0-3 — reads A(s0,0-3) + all B(s0); stage A(t+1)
    LDA_GRP(0, 0);
    LDB_GRP(0, 0, bf01);
    LDB_GRP(0, 2, bf23);
    stage(Abase, 0, kof1, AOFF(1, 0));
    stage(Abase, 128, kof1, AOFF(1, 1));
    MIDBAR();
    MFMA32(0);
    ENDBAR();

    // MPH2: tile t, rows 4-7 — stage B(t+2); counted wait
    LDA_GRP(0, 4);
    if (!last) {
      stage(Bbase, 0, kof2, BOFF(0, 0));
      stage(Bbase, 128, kof2, BOFF(0, 1));
      asm volatile("s_waitcnt vmcnt(4)" ::: "memory");  // A(t+1),B(t+1) landed
    } else {
      asm volatile("s_waitcnt vmcnt(0)" ::: "memory");
    }
    MIDBAR();
    MFMA32(4);
    ENDBAR();

    // MPH3: tile t+1, rows 0-3 — stage A(t+2)
    LDA_GRP(1, 0);
    LDB_GRP(1, 0, bf01);
    LDB_GRP(1, 2, bf23);
    if (!last) {
      stage(Abase, 0, kof2, AOFF(0, 0));
      stage(Abase, 128, kof2, AOFF(0, 1));
    }
    MIDBAR();
    MFMA32(0);
    ENDBAR();

    // MPH4: tile t+1, rows 4-7 — stage B(t+3); counted wait
    LDA_GRP(1, 4);
    if (!last) {
      stage(Bbase, 0, kof3, BOFF(1, 0));
      stage(Bbase, 128, kof3, BOFF(1, 1));
      asm volatile("s_waitcnt vmcnt(4)" ::: "memory");  // A(t+2),B(t+2) landed
    }
    MIDBAR();
    MFMA32(4);
    ENDBAR();
  }

  // epilogue (swapped layout): M = lane&15, N = (lane>>4)*4 + j -> float4
  const int r4 = (lane >> 4) * 4;
#pragma unroll
  for (int n = 0; n < 4; ++n) {
    const int cc = bcol + wc * 64 + n * 16 + r4;
    const f32x4 bv = *reinterpret_cast<const f32x4*>(bias + cc);
#pragma unroll
    for (int m = 0; m < 8; ++m) {
      const int rr = brow + wr * 128 + m * 16 + l15;
      f32x4 o = acc[m][n] + bv;
      *reinterpret_cast<f32x4*>(C + (size_t)rr * N + cc) = o;
    }
  }
}

// ---------------------------------------------------------------------------

extern "C" void kernel_launch(void* const* d_in, const int* in_sizes, int n_in,
                              void* d_out, int out_size, void* d_ws, size_t ws_size,
                              hipStream_t stream) {
  const float* x = (const float*)d_in[0];
  const float* wA = (const float*)d_in[1];
  const float* wB = (const float*)d_in[2];
  const float* bias = (const float*)d_in[3];
  const float* scaleA = (const float*)d_in[4];
  const float* scaleB = (const float*)d_in[5];
  float* out = (float*)d_out;

  char* ws = (char*)d_ws;
  _Float16* waT = (_Float16*)ws;                                  // 8 MB
  _Float16* wbs = (_Float16*)(ws + (size_t)RANK * IN_FEAT * 2);   // 8 MB
  _Float16* xp =
      (_Float16*)(ws + (size_t)RANK * IN_FEAT * 2 + (size_t)OUT_FEAT * RANK * 2);  // 16 MB
  _Float16* x16 = (_Float16*)(ws + (size_t)RANK * IN_FEAT * 2 +
                              (size_t)OUT_FEAT * RANK * 2 + (size_t)TOK * RANK * 2);  // 64 MB
  const size_t needed = (size_t)RANK * IN_FEAT * 2 + (size_t)OUT_FEAT * RANK * 2 +
                        (size_t)TOK * RANK * 2 + (size_t)TOK * IN_FEAT * 2;

  hipLaunchKernelGGL(sparsify_A_kernel, dim3((IN_FEAT * RANK / 4) / 256), dim3(256),
                     0, stream, wA, scaleA, waT);
  hipLaunchKernelGGL(sparsify_B_kernel, dim3((OUT_FEAT * RANK / 4) / 256), dim3(256),
                     0, stream, wB, scaleB, wbs);

  if (ws_size >= needed) {
    hipLaunchKernelGGL(cast_x_kernel, dim3((TOK * IN_FEAT / 8) / 256), dim3(256),
                       0, stream, x, x16);
    // GEMM1: xp(f16) = x16 @ waT^T — 1-phase/K-tile triple-buffered kernel
    (void)hipFuncSetAttribute(
        reinterpret_cast<const void*>(&gemm1_m<TOK, RANK, IN_FEAT>),
        hipFuncAttributeMaxDynamicSharedMemorySize, 147456);
    hipLaunchKernelGGL((gemm1_m<TOK, RANK, IN_FEAT>),
                       dim3(RANK / 256, TOK / 128), dim3(512), 147456, stream,
                       x16, waT, xp);
  } else {
    hipLaunchKernelGGL((gemm128<RANK, IN_FEAT, true, true>),
                       dim3(RANK / 128, TOK / 128), dim3(256), 0, stream,
                       (const void*)x, waT, (void*)xp, nullptr);
  }

  // GEMM2: out(fp32) = x_proj @ wbs^T + bias — merged 4-phase 256^2 kernel
  (void)hipFuncSetAttribute(
      reinterpret_cast<const void*>(&gemm2_m<TOK, OUT_FEAT, RANK>),
      hipFuncAttributeMaxDynamicSharedMemorySize, 131072);
  hipLaunchKernelGGL((gemm2_m<TOK, OUT_FEAT, RANK>),
                     dim3(OUT_FEAT / 256, TOK / 256), dim3(512), 131072, stream,
                     xp, wbs, out, bias);
}

// Round 6
// 194.314 us; speedup vs baseline: 1.0539x; 1.0539x over previous
//
#include <hip/hip_runtime.h>

#define IN_FEAT 4096
#define OUT_FEAT 4096
#define RANK 1024
#define TOK 8192   // B*S = 4*2048

typedef _Float16 f16x8 __attribute__((ext_vector_type(8)));
typedef _Float16 f16x4 __attribute__((ext_vector_type(4)));
typedef float f32x4 __attribute__((ext_vector_type(4)));

#define GLD_LDS16(g, l)                                                         \
  __builtin_amdgcn_global_load_lds(                                             \
      (__attribute__((address_space(1))) const void*)(g),                       \
      (__attribute__((address_space(3))) void*)(l), 16, 0, 0)

#define MIDBAR()                                        \
  __builtin_amdgcn_s_barrier();                         \
  asm volatile("s_waitcnt lgkmcnt(0)" ::: "memory")
#define ENDBAR() __builtin_amdgcn_s_barrier()

// ---------------------------------------------------------------------------
// 2:4 soft-threshold sparsify, scale, cast to fp16.
// ---------------------------------------------------------------------------

__device__ __forceinline__ void soft24(const float4 g, float s,
                                       float& r0, float& r1, float& r2, float& r3) {
  const float m0 = fabsf(g.x), m1 = fabsf(g.y), m2 = fabsf(g.z), m3 = fabsf(g.w);
  const float lo1 = fminf(m0, m1), hi1 = fmaxf(m0, m1);
  const float lo2 = fminf(m2, m3), hi2 = fmaxf(m2, m3);
  const float t = fminf(fmaxf(lo1, lo2), fminf(hi1, hi2));  // 2nd smallest
  r0 = copysignf(fmaxf(m0 - t, 0.0f), g.x) * s;
  r1 = copysignf(fmaxf(m1 - t, 0.0f), g.y) * s;
  r2 = copysignf(fmaxf(m2 - t, 0.0f), g.z) * s;
  r3 = copysignf(fmaxf(m3 - t, 0.0f), g.w) * s;
}

__global__ __launch_bounds__(256) void sparsify_A_kernel(
    const float* __restrict__ wA, const float* __restrict__ scaleA,
    _Float16* __restrict__ waT) {
  const int idx = blockIdx.x * 256 + threadIdx.x;
  const int i = idx & (IN_FEAT - 1);
  const int jg = idx >> 12;
  const float4 g = *reinterpret_cast<const float4*>(wA + (size_t)i * RANK + jg * 4);
  const float s = scaleA[0];
  float r0, r1, r2, r3;
  soft24(g, s, r0, r1, r2, r3);
  const size_t base = (size_t)(jg * 4) * IN_FEAT + i;
  waT[base] = (_Float16)r0;
  waT[base + IN_FEAT] = (_Float16)r1;
  waT[base + 2 * IN_FEAT] = (_Float16)r2;
  waT[base + 3 * IN_FEAT] = (_Float16)r3;
}

__global__ __launch_bounds__(256) void sparsify_B_kernel(
    const float* __restrict__ wB, const float* __restrict__ scaleB,
    _Float16* __restrict__ wbs) {
  const int idx = blockIdx.x * 256 + threadIdx.x;
  const float4 g = *reinterpret_cast<const float4*>(wB + (size_t)idx * 4);
  const float s = scaleB[0];
  float r0, r1, r2, r3;
  soft24(g, s, r0, r1, r2, r3);
  f16x4 h;
  h[0] = (_Float16)r0; h[1] = (_Float16)r1; h[2] = (_Float16)r2; h[3] = (_Float16)r3;
  *reinterpret_cast<f16x4*>(wbs + (size_t)idx * 4) = h;
}

// ---------------------------------------------------------------------------
// 128x128-tile GEMM (verified R1/R2) — fallback path only (small ws).
// ---------------------------------------------------------------------------
template <int N, int K, bool A_F32, bool OUT_F16>
__global__ __launch_bounds__(256, 4) void gemm128(
    const void* __restrict__ Av, const _Float16* __restrict__ Bh,
    void* __restrict__ Cv, const float* __restrict__ bias) {
  __shared__ __attribute__((aligned(128))) char lds[32768];
  char* ldsA = lds;
  char* ldsB = lds + 16384;

  const int tid = threadIdx.x;
  const int lane = tid & 63;
  const int w = tid >> 6;
  const int wrow = (w >> 1) * 64;
  const int wcol = (w & 1) * 64;

  constexpr int GX = N / 128;
  const int nwg = GX * (TOK / 128);
  const int l = blockIdx.y * GX + blockIdx.x;
  const int wg = (l & 7) * (nwg >> 3) + (l >> 3);
  const int brow = (wg / GX) * 128;
  const int bcol = (wg % GX) * 128;

  f32x4 acc[4][4] = {};

  for (int k0 = 0; k0 < K; k0 += 64) {
    __syncthreads();
#pragma unroll
    for (int it = 0; it < 4; ++it) {
      const int c = it * 256 + tid;
      const int row = c >> 3;
      const int u = c & 7;
      const _Float16* gsrc =
          Bh + (size_t)(bcol + row) * K + k0 + ((u ^ (row & 7)) << 3);
      GLD_LDS16(gsrc, ldsB + c * 16);
    }
    if constexpr (A_F32) {
      const float* Af = (const float*)Av;
#pragma unroll
      for (int it = 0; it < 4; ++it) {
        const int c = it * 256 + tid;
        const int row = c >> 3;
        const int u = c & 7;
        const float* gsrc = Af + (size_t)(brow + row) * K + k0 + (u << 3);
        const float4 f0 = *reinterpret_cast<const float4*>(gsrc);
        const float4 f1 = *reinterpret_cast<const float4*>(gsrc + 4);
        f16x8 h;
        h[0] = (_Float16)f0.x; h[1] = (_Float16)f0.y;
        h[2] = (_Float16)f0.z; h[3] = (_Float16)f0.w;
        h[4] = (_Float16)f1.x; h[5] = (_Float16)f1.y;
        h[6] = (_Float16)f1.z; h[7] = (_Float16)f1.w;
        *reinterpret_cast<f16x8*>(ldsA + row * 128 + ((u ^ (row & 7)) << 4)) = h;
      }
    } else {
      const _Float16* Ah = (const _Float16*)Av;
#pragma unroll
      for (int it = 0; it < 4; ++it) {
        const int c = it * 256 + tid;
        const int row = c >> 3;
        const int u = c & 7;
        const _Float16* gsrc =
            Ah + (size_t)(brow + row) * K + k0 + ((u ^ (row & 7)) << 3);
        GLD_LDS16(gsrc, ldsA + c * 16);
      }
    }
    __syncthreads();
#pragma unroll
    for (int kk = 0; kk < 2; ++kk) {
      f16x8 af[4], bf[4];
#pragma unroll
      for (int m = 0; m < 4; ++m) {
        const int row = wrow + m * 16 + (lane & 15);
        const int u = (kk * 4 + (lane >> 4)) ^ (row & 7);
        af[m] = *reinterpret_cast<const f16x8*>(ldsA + row * 128 + u * 16);
      }
#pragma unroll
      for (int n = 0; n < 4; ++n) {
        const int row = wcol + n * 16 + (lane & 15);
        const int u = (kk * 4 + (lane >> 4)) ^ (row & 7);
        bf[n] = *reinterpret_cast<const f16x8*>(ldsB + row * 128 + u * 16);
      }
#pragma unroll
      for (int m = 0; m < 4; ++m)
#pragma unroll
        for (int n = 0; n < 4; ++n)
          acc[m][n] =
              __builtin_amdgcn_mfma_f32_16x16x32_f16(af[m], bf[n], acc[m][n], 0, 0, 0);
    }
  }

  const int r4 = (lane >> 4) * 4;
  const int cl = lane & 15;
  if constexpr (OUT_F16) {
    _Float16* C = (_Float16*)Cv;
#pragma unroll
    for (int m = 0; m < 4; ++m)
#pragma unroll
      for (int n = 0; n < 4; ++n)
#pragma unroll
        for (int j = 0; j < 4; ++j) {
          const int rr = brow + wrow + m * 16 + r4 + j;
          const int cc = bcol + wcol + n * 16 + cl;
          C[(size_t)rr * N + cc] = (_Float16)acc[m][n][j];
        }
  } else {
    float* C = (float*)Cv;
#pragma unroll
    for (int n = 0; n < 4; ++n) {
      const int cc = bcol + wcol + n * 16 + cl;
      const float bv = bias[cc];
#pragma unroll
      for (int m = 0; m < 4; ++m)
#pragma unroll
        for (int j = 0; j < 4; ++j) {
          const int rr = brow + wrow + m * 16 + r4 + j;
          C[(size_t)rr * N + cc] = acc[m][n][j] + bv;
        }
    }
  }
}

// ---------------------------------------------------------------------------
// GEMM1 fused-cast: C(f16) = cast16(A_f32) @ B^T.  128(M)x256(N)-tile,
// 1 phase/K-tile, triple-buffered LDS (A 3x16KB @0, B 3x32KB @49152 = 144 KB).
// A is fp32: reg-staged (2x float4 loads -> cvt -> swizzled ds_write_b128).
// Per tile t: ds_reads(t) | writeA(t+1) [regs from t-1, compiler auto-vmcnt]
//           | issue A(t+2) regs + stage B(t+2) | vmcnt(8) [B(t+1) landed]
//           | MIDBAR | 32 MFMA (swapped operands) | ENDBAR.
// Slot being written, (t+1)%3 == (t-2)%3, last read at t-2 (>=1 barrier ago).
// ---------------------------------------------------------------------------
template <int M, int N, int K>
__global__ __launch_bounds__(512, 2) void gemm1_f(
    const float* __restrict__ A, const _Float16* __restrict__ B,
    _Float16* __restrict__ C) {
  extern __shared__ char lds[];

  const int tid = threadIdx.x;
  const int lane = tid & 63;
  const int w = tid >> 6;
  const int wr = w >> 2;   // 0..1 (M)
  const int wc = w & 3;    // 0..3 (N)
  const int l15 = lane & 15;
  const int ubase = lane >> 4;

  constexpr int GX = N / 256;           // 4
  constexpr int NWG = GX * (M / 128);   // 256
  const int l = blockIdx.y * GX + blockIdx.x;
  const int wg = (l & 7) * (NWG >> 3) + (l >> 3);
  const int brow = (wg / GX) * 128;
  const int bcol = (wg % GX) * 256;

  f32x4 acc[4][4] = {};
  f16x8 af[4][2], bf[4][2];

  // A reg-stage: 2 granules of 16B-f16 (=8 f32) per lane
  const int ar0 = tid >> 3, au0 = tid & 7;            // granule 0: rows 0..63
  const int ar1 = (512 + tid) >> 3, au1 = tid & 7;    // granule 1: rows 64..127
  float4 a0l, a0h, a1l, a1h;

  auto issueA = [&](int kof) {
    const float* p0 = A + (size_t)(brow + ar0) * K + kof + au0 * 8;
    const float* p1 = A + (size_t)(brow + ar1) * K + kof + au1 * 8;
    a0l = *reinterpret_cast<const float4*>(p0);
    a0h = *reinterpret_cast<const float4*>(p0 + 4);
    a1l = *reinterpret_cast<const float4*>(p1);
    a1h = *reinterpret_cast<const float4*>(p1 + 4);
  };
  auto writeA = [&](int slot) {
    f16x8 h0, h1;
    h0[0] = (_Float16)a0l.x; h0[1] = (_Float16)a0l.y;
    h0[2] = (_Float16)a0l.z; h0[3] = (_Float16)a0l.w;
    h0[4] = (_Float16)a0h.x; h0[5] = (_Float16)a0h.y;
    h0[6] = (_Float16)a0h.z; h0[7] = (_Float16)a0h.w;
    h1[0] = (_Float16)a1l.x; h1[1] = (_Float16)a1l.y;
    h1[2] = (_Float16)a1l.z; h1[3] = (_Float16)a1l.w;
    h1[4] = (_Float16)a1h.x; h1[5] = (_Float16)a1h.y;
    h1[6] = (_Float16)a1h.z; h1[7] = (_Float16)a1h.w;
    *reinterpret_cast<f16x8*>(lds + slot * 16384 + ar0 * 128 +
                              ((au0 ^ (ar0 & 7)) << 4)) = h0;
    *reinterpret_cast<f16x8*>(lds + slot * 16384 + ar1 * 128 +
                              ((au1 ^ (ar1 & 7)) << 4)) = h1;
  };
  auto stageB = [&](int kof, int slot) {
#pragma unroll
    for (int r = 0; r < 4; ++r) {
      const int c = r * 512 + tid;
      const int row = c >> 3;
      const int u = c & 7;
      GLD_LDS16(B + (size_t)(bcol + row) * K + kof + ((u ^ (row & 7)) << 3),
                lds + 49152 + slot * 32768 + c * 16);
    }
  };

  constexpr int NT = K / 64;  // 64 K-tiles

  // ---- prologue ----
  issueA(0);                 // A(0) regs
  stageB(0, 0);              // B(0)
  asm volatile("s_waitcnt vmcnt(4)" ::: "memory");  // A(0) landed, B(0) in flight
  writeA(0);                 // A(0) -> slot0
  issueA(64);                // A(1) regs
  stageB(64, 1);             // B(1)
  asm volatile("s_waitcnt vmcnt(8)" ::: "memory");  // B(0) landed; A(1)+B(1) fly
  asm volatile("s_waitcnt lgkmcnt(0)" ::: "memory");  // A(0) write done
  __builtin_amdgcn_s_barrier();

  int slot = 0;
  for (int t = 0; t < NT; ++t) {
    // 1. ds-reads for tile t (16 x ds_read_b128)
#pragma unroll
    for (int i = 0; i < 4; ++i)
#pragma unroll
      for (int ks = 0; ks < 2; ++ks) {
        const int row = wr * 64 + i * 16 + l15;
        const int u = (ks * 4 + ubase) ^ (row & 7);
        af[i][ks] =
            *reinterpret_cast<const f16x8*>(lds + slot * 16384 + row * 128 + u * 16);
      }
#pragma unroll
    for (int j = 0; j < 4; ++j)
#pragma unroll
      for (int ks = 0; ks < 2; ++ks) {
        const int row = wc * 64 + j * 16 + l15;
        const int u = (ks * 4 + ubase) ^ (row & 7);
        bf[j][ks] = *reinterpret_cast<const f16x8*>(lds + 49152 + slot * 32768 +
                                                    row * 128 + u * 16);
      }
    // 2. write A(t+1) into slot (t+1)%3 (compiler drains its loads via reg dep)
    if (t + 1 < NT) {
      int s1 = slot + 1;
      if (s1 >= 3) s1 -= 3;
      writeA(s1);
    }
    // 3. issue A(t+2) + stage B(t+2) into slot (t+2)%3; counted wait
    if (t + 2 < NT) {
      int s2 = slot + 2;
      if (s2 >= 3) s2 -= 3;
      issueA((t + 2) * 64);
      stageB((t + 2) * 64, s2);
      asm volatile("s_waitcnt vmcnt(8)" ::: "memory");  // B(t+1) landed
    } else {
      asm volatile("s_waitcnt vmcnt(0)" ::: "memory");  // drain last B
    }
    MIDBAR();
    __builtin_amdgcn_s_setprio(1);
#pragma unroll
    for (int ks = 0; ks < 2; ++ks)
#pragma unroll
      for (int i = 0; i < 4; ++i)
#pragma unroll
        for (int j = 0; j < 4; ++j)
          acc[i][j] = __builtin_amdgcn_mfma_f32_16x16x32_f16(
              bf[j][ks], af[i][ks], acc[i][j], 0, 0, 0);  // swapped operands
    __builtin_amdgcn_s_setprio(0);
    ENDBAR();
    ++slot;
    if (slot == 3) slot = 0;
  }

  // epilogue (swapped layout): M = lane&15, N = (lane>>4)*4 + j
  const int r4 = (lane >> 4) * 4;
#pragma unroll
  for (int m = 0; m < 4; ++m)
#pragma unroll
    for (int n = 0; n < 4; ++n) {
      const int rr = brow + wr * 64 + m * 16 + l15;
      const int cc = bcol + wc * 64 + n * 16 + r4;
      f16x4 h;
#pragma unroll
      for (int j = 0; j < 4; ++j) h[j] = (_Float16)acc[m][n][j];
      *reinterpret_cast<f16x4*>(C + (size_t)rr * N + cc) = h;
    }
}

// ---------------------------------------------------------------------------
// GEMM2: 256x256-tile, merged 4 phases per 2 K-tiles (verified R5).
// ---------------------------------------------------------------------------
#define AOFF(s, h) (((s) * 2 + (h)) * 16384)
#define BOFF(s, h) (65536 + ((s) * 2 + (h)) * 16384)

template <int M, int N, int K>
__global__ __launch_bounds__(512, 2) void gemm2_m(
    const _Float16* __restrict__ A, const _Float16* __restrict__ B,
    float* __restrict__ C, const float* __restrict__ bias) {
  extern __shared__ char lds[];

  const int tid = threadIdx.x;
  const int lane = tid & 63;
  const int w = tid >> 6;
  const int wr = w >> 2;
  const int wc = w & 3;
  const int l15 = lane & 15;
  const int ubase = lane >> 4;

  constexpr int GX = N / 256;
  constexpr int NWG = GX * (M / 256);
  const int l = blockIdx.y * GX + blockIdx.x;
  const int wg = (l & 7) * (NWG >> 3) + (l >> 3);
  const int brow = (wg / GX) * 256;
  const int bcol = (wg % GX) * 256;

  const _Float16* Abase = A + (size_t)brow * K;
  const _Float16* Bbase = B + (size_t)bcol * K;

  auto stage = [&](const _Float16* srcBase, int rowOff, int kof, int ldsOff) {
#pragma unroll
    for (int r = 0; r < 2; ++r) {
      const int c = r * 512 + tid;
      const int row = c >> 3;
      const int u = c & 7;
      const _Float16* g =
          srcBase + (size_t)(rowOff + row) * K + kof + ((u ^ (row & 7)) << 3);
      GLD_LDS16(g, lds + ldsOff + c * 16);
    }
  };

  f32x4 acc[8][4] = {};
  f16x8 af[4][2], bf01[2][2], bf23[2][2];

#define LDA_GRP(SLOT, MBASE)                                                   \
  _Pragma("unroll") for (int i = 0; i < 4; ++i)                                \
  _Pragma("unroll") for (int ks = 0; ks < 2; ++ks) {                           \
    const int row = ((MBASE) + i) * 16 + l15;                                  \
    const int u = (ks * 4 + ubase) ^ (row & 7);                                \
    af[i][ks] = *reinterpret_cast<const f16x8*>(                               \
        lds + AOFF(SLOT, wr) + row * 128 + u * 16);                            \
  }
#define LDB_GRP(SLOT, NBASE, DST)                                              \
  _Pragma("unroll") for (int j = 0; j < 2; ++j)                                \
  _Pragma("unroll") for (int ks = 0; ks < 2; ++ks) {                           \
    const int row = (wc & 1) * 64 + ((NBASE) + j) * 16 + l15;                  \
    const int u = (ks * 4 + ubase) ^ (row & 7);                                \
    DST[j][ks] = *reinterpret_cast<const f16x8*>(                              \
        lds + BOFF(SLOT, wc >> 1) + row * 128 + u * 16);                       \
  }

#define MFMA32(MO)                                                             \
  __builtin_amdgcn_s_setprio(1);                                               \
  _Pragma("unroll") for (int ks = 0; ks < 2; ++ks)                             \
  _Pragma("unroll") for (int i = 0; i < 4; ++i)                                \
  _Pragma("unroll") for (int j = 0; j < 2; ++j) {                              \
    acc[(MO) + i][j] = __builtin_amdgcn_mfma_f32_16x16x32_f16(                 \
        bf01[j][ks], af[i][ks], acc[(MO) + i][j], 0, 0, 0);                    \
    acc[(MO) + i][2 + j] = __builtin_amdgcn_mfma_f32_16x16x32_f16(             \
        bf23[j][ks], af[i][ks], acc[(MO) + i][2 + j], 0, 0, 0);                \
  }                                                                            \
  __builtin_amdgcn_s_setprio(0);

  constexpr int NT = K / 64;

  stage(Abase, 0, 0, AOFF(0, 0));
  stage(Abase, 128, 0, AOFF(0, 1));
  stage(Bbase, 0, 0, BOFF(0, 0));
  stage(Bbase, 128, 0, BOFF(0, 1));
  stage(Bbase, 0, 64, BOFF(1, 0));
  stage(Bbase, 128, 64, BOFF(1, 1));
  asm volatile("s_waitcnt vmcnt(4)" ::: "memory");
  __builtin_amdgcn_s_barrier();

  for (int tt = 0; tt < NT; tt += 2) {
    const bool last = (tt + 2 >= NT);
    const int kof1 = tt * 64 + 64;
    const int kof2 = tt * 64 + 128;
    const int kof3 = tt * 64 + 192;

    LDA_GRP(0, 0);
    LDB_GRP(0, 0, bf01);
    LDB_GRP(0, 2, bf23);
    stage(Abase, 0, kof1, AOFF(1, 0));
    stage(Abase, 128, kof1, AOFF(1, 1));
    MIDBAR();
    MFMA32(0);
    ENDBAR();

    LDA_GRP(0, 4);
    if (!last) {
      stage(Bbase, 0, kof2, BOFF(0, 0));
      stage(Bbase, 128, kof2, BOFF(0, 1));
      asm volatile("s_waitcnt vmcnt(4)" ::: "memory");
    } else {
      asm volatile("s_waitcnt vmcnt(0)" ::: "memory");
    }
    MIDBAR();
    MFMA32(4);
    ENDBAR();

    LDA_GRP(1, 0);
    LDB_GRP(1, 0, bf01);
    LDB_GRP(1, 2, bf23);
    if (!last) {
      stage(Abase, 0, kof2, AOFF(0, 0));
      stage(Abase, 128, kof2, AOFF(0, 1));
    }
    MIDBAR();
    MFMA32(0);
    ENDBAR();

    LDA_GRP(1, 4);
    if (!last) {
      stage(Bbase, 0, kof3, BOFF(1, 0));
      stage(Bbase, 128, kof3, BOFF(1, 1));
      asm volatile("s_waitcnt vmcnt(4)" ::: "memory");
    }
    MIDBAR();
    MFMA32(4);
    ENDBAR();
  }

  const int r4 = (lane >> 4) * 4;
#pragma unroll
  for (int n = 0; n < 4; ++n) {
    const int cc = bcol + wc * 64 + n * 16 + r4;
    const f32x4 bv = *reinterpret_cast<const f32x4*>(bias + cc);
#pragma unroll
    for (int m = 0; m < 8; ++m) {
      const int rr = brow + wr * 128 + m * 16 + l15;
      f32x4 o = acc[m][n] + bv;
      *reinterpret_cast<f32x4*>(C + (size_t)rr * N + cc) = o;
    }
  }
}

// ---------------------------------------------------------------------------

extern "C" void kernel_launch(void* const* d_in, const int* in_sizes, int n_in,
                              void* d_out, int out_size, void* d_ws, size_t ws_size,
                              hipStream_t stream) {
  const float* x = (const float*)d_in[0];
  const float* wA = (const float*)d_in[1];
  const float* wB = (const float*)d_in[2];
  const float* bias = (const float*)d_in[3];
  const float* scaleA = (const float*)d_in[4];
  const float* scaleB = (const float*)d_in[5];
  float* out = (float*)d_out;

  char* ws = (char*)d_ws;
  _Float16* waT = (_Float16*)ws;                                  // 8 MB
  _Float16* wbs = (_Float16*)(ws + (size_t)RANK * IN_FEAT * 2);   // 8 MB
  _Float16* xp =
      (_Float16*)(ws + (size_t)RANK * IN_FEAT * 2 + (size_t)OUT_FEAT * RANK * 2);  // 16 MB
  const size_t needed = (size_t)RANK * IN_FEAT * 2 + (size_t)OUT_FEAT * RANK * 2 +
                        (size_t)TOK * RANK * 2;

  hipLaunchKernelGGL(sparsify_A_kernel, dim3((IN_FEAT * RANK / 4) / 256), dim3(256),
                     0, stream, wA, scaleA, waT);
  hipLaunchKernelGGL(sparsify_B_kernel, dim3((OUT_FEAT * RANK / 4) / 256), dim3(256),
                     0, stream, wB, scaleB, wbs);

  if (ws_size >= needed) {
    // GEMM1 (fused cast): xp(f16) = cast16(x) @ waT^T
    (void)hipFuncSetAttribute(
        reinterpret_cast<const void*>(&gemm1_f<TOK, RANK, IN_FEAT>),
        hipFuncAttributeMaxDynamicSharedMemorySize, 147456);
    hipLaunchKernelGGL((gemm1_f<TOK, RANK, IN_FEAT>),
                       dim3(RANK / 256, TOK / 128), dim3(512), 147456, stream,
                       x, waT, xp);
  } else {
    hipLaunchKernelGGL((gemm128<RANK, IN_FEAT, true, true>),
                       dim3(RANK / 128, TOK / 128), dim3(256), 0, stream,
                       (const void*)x, waT, (void*)xp, nullptr);
  }

  // GEMM2: out(fp32) = x_proj @ wbs^T + bias — merged 4-phase 256^2 kernel
  (void)hipFuncSetAttribute(
      reinterpret_cast<const void*>(&gemm2_m<TOK, OUT_FEAT, RANK>),
      hipFuncAttributeMaxDynamicSharedMemorySize, 131072);
  hipLaunchKernelGGL((gemm2_m<TOK, OUT_FEAT, RANK>),
                     dim3(OUT_FEAT / 256, TOK / 256), dim3(512), 131072, stream,
                     xp, wbs, out, bias);
}